// Round 14
// baseline (242.801 us; speedup 1.0000x reference)
//
#include <hip/hip_runtime.h>
#include <hip/hip_bf16.h>

#define Bsz 4
#define Nn 2048
#define Dd 512
#define Hh 8
#define HDim 64
#define MTOT (Bsz * Nn)  // 8192

typedef unsigned short ush;
typedef __bf16 bf16x8 __attribute__((ext_vector_type(8)));
typedef float f32x4 __attribute__((ext_vector_type(4)));

__device__ __forceinline__ ush f2bf(float f) {
    unsigned u = __builtin_bit_cast(unsigned, f);
    unsigned r = (u + 0x7fffu + ((u >> 16) & 1u)) >> 16;
    return (ush)r;
}
__device__ __forceinline__ unsigned cvtpk(float a, float b) {
    unsigned r;
    asm("v_cvt_pk_bf16_f32 %0, %1, %2" : "=v"(r) : "v"(a), "v"(b));
    return r;
}

#define GLOAD_LDS(g, l)                                                       \
    __builtin_amdgcn_global_load_lds(                                         \
        (const __attribute__((address_space(1))) unsigned int*)(g),           \
        (__attribute__((address_space(3))) unsigned int*)(l), 16, 0, 0)

// ---------------- convert f32 -> bf16 ----------------
__global__ __launch_bounds__(256) void convert_bf16(const float* __restrict__ src,
                                                    ush* __restrict__ dst, int n) {
    int i = (blockIdx.x * 256 + threadIdx.x) * 4;
    if (i < n) {
        float4 v = *reinterpret_cast<const float4*>(src + i);
        dst[i + 0] = f2bf(v.x);
        dst[i + 1] = f2bf(v.y);
        dst[i + 2] = f2bf(v.z);
        dst[i + 3] = f2bf(v.w);
    }
}

// ---------------- transpose-convert 4x W f32[k][n] -> Wt bf16[n][k] (z picks W) ------
__global__ __launch_bounds__(256) void transpose_bf16(const float* __restrict__ W0,
                                                      const float* __restrict__ W1,
                                                      const float* __restrict__ W2,
                                                      const float* __restrict__ W3,
                                                      ush* __restrict__ D0,
                                                      ush* __restrict__ D1,
                                                      ush* __restrict__ D2,
                                                      ush* __restrict__ D3) {
    const int z = blockIdx.z;
    const float* src = (z == 0) ? W0 : (z == 1) ? W1 : (z == 2) ? W2 : W3;
    ush* dst = (z == 0) ? D0 : (z == 1) ? D1 : (z == 2) ? D2 : D3;
    __shared__ ush tile[64][72];
    const int k0 = blockIdx.x * 64, n0 = blockIdx.y * 64;
    const int t = threadIdx.x;
    const int r = t >> 2, c = (t & 3) * 16;
#pragma unroll
    for (int i = 0; i < 4; ++i) {
        float4 v = *reinterpret_cast<const float4*>(src + (size_t)(k0 + r) * Dd + n0 + c + i * 4);
        tile[r][c + i * 4 + 0] = f2bf(v.x);
        tile[r][c + i * 4 + 1] = f2bf(v.y);
        tile[r][c + i * 4 + 2] = f2bf(v.z);
        tile[r][c + i * 4 + 3] = f2bf(v.w);
    }
    __syncthreads();
    const int rn = t >> 2, kc = (t & 3) * 16;
    ush ov[16];
#pragma unroll
    for (int j = 0; j < 16; ++j) ov[j] = tile[kc + j][rn];
    *reinterpret_cast<uint4*>(dst + (size_t)(n0 + rn) * Dd + k0 + kc) =
        *reinterpret_cast<uint4*>(&ov[0]);
    *reinterpret_cast<uint4*>(dst + (size_t)(n0 + rn) * Dd + k0 + kc + 8) =
        *reinterpret_cast<uint4*>(&ov[8]);
}

// ---------------- adj int32 -> bitmask ----------------
__global__ __launch_bounds__(256) void adj_to_bits(const int* __restrict__ adj,
                                                   unsigned* __restrict__ bits) {
    int idx = blockIdx.x * 256 + threadIdx.x;
    const int* p = adj + (size_t)(idx >> 6) * Nn + (idx & 63) * 32;
    unsigned m = 0;
#pragma unroll
    for (int v4 = 0; v4 < 8; ++v4) {
        int4 v = *reinterpret_cast<const int4*>(p + v4 * 4);
        if (v.x) m |= 1u << (v4 * 4 + 0);
        if (v.y) m |= 1u << (v4 * 4 + 1);
        if (v.z) m |= 1u << (v4 * 4 + 2);
        if (v.w) m |= 1u << (v4 * 4 + 3);
    }
    bits[idx] = m;
}

// ---------------- 128x128 bf16 GEMM, compile-time K-loop (full unroll) ----------------
// Hoisted per-lane global pointers; constant element offsets fold into the instruction's
// 13-bit offset field after unroll -> no addressing VALU in the steady-state loop.
// FUSED=1: A=xb, Wt=Wqkv^T[1536][512]; blockIdx.y>>2 selects Q/K/V epilogue.
// FUSED=0: A=Ob, Wt=Wo^T; split-K via blockIdx.z; f32 partials outF/outF2.
template <int FUSED, int KITERS>
__global__ __launch_bounds__(256) void gemm128(const ush* __restrict__ A,
                                               const ush* __restrict__ Wt,
                                               const float* __restrict__ bq,
                                               const float* __restrict__ bk,
                                               const float* __restrict__ bv,
                                               ush* __restrict__ outQ,
                                               ush* __restrict__ outK,
                                               ush* __restrict__ outVt,
                                               float* __restrict__ outF,
                                               float* __restrict__ outF2) {
    __shared__ __align__(16) ush As[2][128][32];
    __shared__ __align__(16) ush Bs[2][128][32];
    const int t = threadIdx.x, lane = t & 63, w = t >> 6;
    const int ln = lane & 15, gr = lane >> 4;
    const int m0 = blockIdx.x * 128, n0 = blockIdx.y * 128;
    const int kbase = blockIdx.z * KITERS * 32;
    const int wm = w >> 1, wn = w & 1;  // 2x2 wave grid, 64x64 out each

    f32x4 acc[4][4] = {};
    const int srow = lane >> 2;   // 16 rows per gload instr
    const int cpos = lane & 3;    // 16B chunk slot within LDS row
    const int row0 = w * 16 + srow;
    const int ck = (cpos ^ ((row0 >> 1) & 3)) * 8;  // src pre-swizzle ((row+64) keeps key)

    const ush* aptr0 = A + (size_t)(m0 + row0) * Dd + kbase + ck;
    const ush* aptr1 = aptr0 + (size_t)64 * Dd;
    const ush* bptr0 = Wt + (size_t)(n0 + row0) * Dd + kbase + ck;
    const ush* bptr1 = bptr0 + (size_t)64 * Dd;

    GLOAD_LDS(aptr0, &As[0][w * 16][0]);
    GLOAD_LDS(aptr1, &As[0][64 + w * 16][0]);
    GLOAD_LDS(bptr0, &Bs[0][w * 16][0]);
    GLOAD_LDS(bptr1, &Bs[0][64 + w * 16][0]);
    __syncthreads();

    const int fchk = (gr ^ ((ln >> 1) & 3)) * 8;  // swizzled fragment chunk

#pragma unroll
    for (int it = 0; it < KITERS; ++it) {
        const int buf = it & 1;
        if (it < KITERS - 1) {
            GLOAD_LDS(aptr0 + (it + 1) * 32, &As[buf ^ 1][w * 16][0]);
            GLOAD_LDS(aptr1 + (it + 1) * 32, &As[buf ^ 1][64 + w * 16][0]);
            GLOAD_LDS(bptr0 + (it + 1) * 32, &Bs[buf ^ 1][w * 16][0]);
            GLOAD_LDS(bptr1 + (it + 1) * 32, &Bs[buf ^ 1][64 + w * 16][0]);
        }
        bf16x8 af[4], bf_[4];
#pragma unroll
        for (int i = 0; i < 4; ++i)
            af[i] = *reinterpret_cast<const bf16x8*>(&As[buf][wm * 64 + i * 16 + ln][fchk]);
#pragma unroll
        for (int j = 0; j < 4; ++j)
            bf_[j] = *reinterpret_cast<const bf16x8*>(&Bs[buf][wn * 64 + j * 16 + ln][fchk]);
#pragma unroll
        for (int i = 0; i < 4; ++i)
#pragma unroll
            for (int j = 0; j < 4; ++j)
                acc[i][j] = __builtin_amdgcn_mfma_f32_16x16x32_bf16(af[i], bf_[j], acc[i][j], 0, 0, 0);
        __syncthreads();
    }

    const float SCL = 0.125f * 1.44269504f;
    if (FUSED) {
        const int qkv = blockIdx.y >> 2;
        const float* bias = (qkv == 0) ? bq : ((qkv == 1) ? bk : bv);
        const float scale = (qkv == 0) ? SCL : 1.0f;
#pragma unroll
        for (int i = 0; i < 4; ++i) {
#pragma unroll
            for (int j = 0; j < 4; ++j) {
                int colq = (n0 & 511) + wn * 64 + j * 16 + ln;
                int h = colq >> 6, hd = colq & 63;
                float bi = bias[colq];
                if (qkv == 2) {
                    int row0o = m0 + wm * 64 + i * 16 + gr * 4;
                    int b = row0o >> 11, nidx = row0o & (Nn - 1);
                    unsigned p0 = cvtpk(acc[i][j][0] + bi, acc[i][j][1] + bi);
                    unsigned p1 = cvtpk(acc[i][j][2] + bi, acc[i][j][3] + bi);
                    *reinterpret_cast<uint2*>(
                        outVt + (((size_t)(b * Hh + h)) * HDim + hd) * Nn + nidx) =
                        make_uint2(p0, p1);
                } else {
                    ush* o = (qkv == 0) ? outQ : outK;
#pragma unroll
                    for (int r = 0; r < 4; ++r) {
                        int row = m0 + wm * 64 + i * 16 + gr * 4 + r;
                        int b = row >> 11, nidx = row & (Nn - 1);
                        float v = (acc[i][j][r] + bi) * scale;
                        o[(((size_t)(b * Hh + h)) * Nn + nidx) * HDim + hd] = f2bf(v);
                    }
                }
            }
        }
    } else {
        float* dst = blockIdx.z ? outF2 : outF;
#pragma unroll
        for (int i = 0; i < 4; ++i) {
#pragma unroll
            for (int j = 0; j < 4; ++j) {
                int col = n0 + wn * 64 + j * 16 + ln;
                float bi = blockIdx.z ? 0.f : bq[col];
#pragma unroll
                for (int r = 0; r < 4; ++r) {
                    int row = m0 + wm * 64 + i * 16 + gr * 4 + r;
                    dst[(size_t)row * Dd + col] = acc[i][j][r] + bi;
                }
            }
        }
    }
}

// ---------------- masked flash attention (fixed-shift softmax, XCD-swizzled) --------
__global__ __launch_bounds__(256) void attn_kernel(const ush* __restrict__ Q,
                                                   const ush* __restrict__ K,
                                                   const ush* __restrict__ Vt,
                                                   const unsigned* __restrict__ bits,
                                                   ush* __restrict__ O) {
    __shared__ __align__(16) ush Ktile[2][64][64];
    __shared__ __align__(16) ush Vtile[2][64][64];
    __shared__ __align__(16) ush Pl[4][16][64];
    const int t = threadIdx.x, lane = t & 63, w = t >> 6;
    const int ln = lane & 15, gr = lane >> 4;
    const int blk = (blockIdx.x & 7) * 128 + (blockIdx.x >> 3);  // XCD-chunked (1024%8==0)
    const int qt = blk & 31;
    const int bh = blk >> 5;
    const int b = bh >> 3, h = bh & 7;
    const int q0 = qt * 64 + w * 16;

    const ush* Qb = Q + (size_t)bh * Nn * HDim;
    const ush* Kb = K + (size_t)bh * Nn * HDim;
    const ush* Vb = Vt + (size_t)bh * HDim * Nn;
    const unsigned* rowbits = bits + ((size_t)b * Nn + q0 + ln) * (Nn / 32);

    char* plbase = (char*)&Pl[w][0][0];
    const int lnm = ln & 7;

    const int srow_in_op = lane >> 3;
    const int schk = lane & 7;

#define STAGE_K(buf, kv0)                                                              \
    {                                                                                  \
        _Pragma("unroll") for (int o = 0; o < 2; ++o) {                                \
            int r0 = o * 32 + w * 8;                                                   \
            int rr = r0 + srow_in_op;                                                  \
            int cc = schk ^ (rr & 7);                                                  \
            GLOAD_LDS(Kb + (size_t)((kv0) + rr) * HDim + cc * 8, &Ktile[buf][r0][0]);  \
        }                                                                              \
    }
#define STAGE_V(buf, kv0)                                                              \
    {                                                                                  \
        _Pragma("unroll") for (int o = 0; o < 2; ++o) {                                \
            int r0 = o * 32 + w * 8;                                                   \
            int rr = r0 + srow_in_op;                                                  \
            int cc = schk ^ (rr & 7);                                                  \
            GLOAD_LDS(Vb + (size_t)rr * Nn + (kv0) + cc * 8, &Vtile[buf][r0][0]);      \
        }                                                                              \
    }

    bf16x8 bq0 = *reinterpret_cast<const bf16x8*>(Qb + (size_t)(q0 + ln) * HDim + gr * 8);
    bf16x8 bq1 = *reinterpret_cast<const bf16x8*>(Qb + (size_t)(q0 + ln) * HDim + 32 + gr * 8);

    f32x4 accO[4] = {};
    float lsum = 0.f;

    STAGE_K(0, 0);
    STAGE_V(0, 0);
    __syncthreads();

    for (int step = 0; step < 32; ++step) {
        const int kv0 = step * 64;
        const int buf = step & 1;
        if (step < 31) {
            STAGE_K(buf ^ 1, kv0 + 64);
            STAGE_V(buf ^ 1, kv0 + 64);
        }

        unsigned w0 = rowbits[kv0 >> 5];
        unsigned w1 = rowbits[(kv0 >> 5) + 1];

        f32x4 s[4];
#pragma unroll
        for (int kt = 0; kt < 4; ++kt) {
            bf16x8 a0 = *reinterpret_cast<const bf16x8*>(
                &Ktile[buf][kt * 16 + ln][((gr) ^ lnm) * 8]);
            bf16x8 a1 = *reinterpret_cast<const bf16x8*>(
                &Ktile[buf][kt * 16 + ln][((4 + gr) ^ lnm) * 8]);
            f32x4 z = {};
            z = __builtin_amdgcn_mfma_f32_16x16x32_bf16(a0, bq0, z, 0, 0, 0);
            s[kt] = __builtin_amdgcn_mfma_f32_16x16x32_bf16(a1, bq1, z, 0, 0, 0);
        }

        float p[4][4];
#pragma unroll
        for (int kt = 0; kt < 4; ++kt) {
            unsigned wsel = (kt >= 2) ? w1 : w0;
#pragma unroll
            for (int r = 0; r < 4; ++r) {
                float e = __builtin_amdgcn_exp2f(s[kt][r]);  // already exp2-domain
                int bit = (kt * 16 + 4 * gr + r) & 31;
                float pe = ((wsel >> bit) & 1u) ? e : 0.f;
                p[kt][r] = pe;
                lsum += pe;
            }
        }

#pragma unroll
        for (int kt = 0; kt < 4; ++kt) {
            unsigned pk0 = cvtpk(p[kt][0], p[kt][1]);
            unsigned pk1 = cvtpk(p[kt][2], p[kt][3]);
            int blkw = (2 * kt + (gr >> 1)) ^ lnm;
            *reinterpret_cast<uint2*>(plbase + ln * 128 + blkw * 16 + 8 * (gr & 1)) =
                make_uint2(pk0, pk1);
        }
#pragma unroll
        for (int c = 0; c < 2; ++c) {
            bf16x8 pf = *reinterpret_cast<const bf16x8*>(
                plbase + ln * 128 + (((4 * c + gr) ^ lnm) * 16));
#pragma unroll
            for (int t2 = 0; t2 < 4; ++t2) {
                bf16x8 vf = *reinterpret_cast<const bf16x8*>(
                    &Vtile[buf][t2 * 16 + ln][((c * 4 + gr) ^ lnm) * 8]);
                accO[t2] = __builtin_amdgcn_mfma_f32_16x16x32_bf16(vf, pf, accO[t2], 0, 0, 0);
            }
        }
        __syncthreads();
    }

    lsum += __shfl_xor(lsum, 16);
    lsum += __shfl_xor(lsum, 32);
    float inv = 1.0f / lsum;
#pragma unroll
    for (int t2 = 0; t2 < 4; ++t2) {
        unsigned o0 = cvtpk(accO[t2][0] * inv, accO[t2][1] * inv);
        unsigned o1 = cvtpk(accO[t2][2] * inv, accO[t2][3] * inv);
        int blkw = (2 * t2 + (gr >> 1)) ^ lnm;
        *reinterpret_cast<uint2*>(plbase + ln * 128 + blkw * 16 + 8 * (gr & 1)) =
            make_uint2(o0, o1);
    }
    int qr = lane >> 2, cs = lane & 3;
#pragma unroll
    for (int half = 0; half < 2; ++half) {
        int blkr = (cs * 2 + half) ^ (qr & 7);
        uint4 val = *reinterpret_cast<const uint4*>(plbase + qr * 128 + blkr * 16);
        *reinterpret_cast<uint4*>(O + ((size_t)(b * Nn + qt * 64 + w * 16 + qr)) * Dd +
                                  h * 64 + cs * 16 + half * 8) = val;
    }
#undef STAGE_K
#undef STAGE_V
}

// ---------------- residual + LayerNorm (sums split-K partials) ----------------
__global__ __launch_bounds__(256) void ln_kernel(const float* __restrict__ h0,
                                                 const float* __restrict__ h1,
                                                 const float* __restrict__ x,
                                                 const float* __restrict__ gamma,
                                                 const float* __restrict__ beta,
                                                 float* __restrict__ out) {
    const int row = blockIdx.x;
    const int t = threadIdx.x;
    const float* hr0 = h0 + (size_t)row * Dd;
    const float* hr1 = h1 + (size_t)row * Dd;
    const float* xr = x + (size_t)row * Dd;
    float y0 = hr0[t] + hr1[t] + xr[t];
    float y1 = hr0[t + 256] + hr1[t + 256] + xr[t + 256];

    __shared__ float red[4];
    float s = y0 + y1;
#pragma unroll
    for (int m = 32; m; m >>= 1) s += __shfl_xor(s, m);
    if ((t & 63) == 0) red[t >> 6] = s;
    __syncthreads();
    float mu = (red[0] + red[1] + red[2] + red[3]) * (1.0f / Dd);

    float d0 = y0 - mu, d1 = y1 - mu;
    float vs = d0 * d0 + d1 * d1;
#pragma unroll
    for (int m = 32; m; m >>= 1) vs += __shfl_xor(vs, m);
    __syncthreads();
    if ((t & 63) == 0) red[t >> 6] = vs;
    __syncthreads();
    float var = (red[0] + red[1] + red[2] + red[3]) * (1.0f / Dd);
    float rs = rsqrtf(var + 1e-5f);

    out[(size_t)row * Dd + t] = d0 * rs * gamma[t] + beta[t];
    out[(size_t)row * Dd + t + 256] = d1 * rs * gamma[t + 256] + beta[t + 256];
}

extern "C" void kernel_launch(void* const* d_in, const int* in_sizes, int n_in,
                              void* d_out, int out_size, void* d_ws, size_t ws_size,
                              hipStream_t stream) {
    const float* x = (const float*)d_in[0];
    const int* adj = (const int*)d_in[1];
    const float* Wq = (const float*)d_in[2];
    const float* bq = (const float*)d_in[3];
    const float* Wk = (const float*)d_in[4];
    const float* bk = (const float*)d_in[5];
    const float* Wv = (const float*)d_in[6];
    const float* bv = (const float*)d_in[7];
    const float* Wo = (const float*)d_in[8];
    const float* bo = (const float*)d_in[9];
    const float* gamma = (const float*)d_in[10];
    const float* beta = (const float*)d_in[11];
    float* out = (float*)d_out;

    const size_t MD = (size_t)MTOT * Dd;  // 4194304
    const size_t WW = (size_t)Dd * Dd;    // 262144
    ush* ws = (ush*)d_ws;
    ush* xb = ws;
    ush* Wqkvb = xb + MD;        // [1536][512] = Wq^T | Wk^T | Wv^T
    ush* Wob = Wqkvb + 3 * WW;
    ush* Qb = Wob + WW;
    ush* Kb = Qb + MD;
    ush* Vtb = Kb + MD;
    ush* Ob = Vtb + MD;
    float* hbuf = (float*)(Ob + MD);
    unsigned* bitsbuf = (unsigned*)hbuf;  // consumed by attn before O-proj writes hbuf
    float* hbuf2 = (float*)Qb;            // split-K partial aliases Q/K (dead after attn)

    convert_bf16<<<dim3((int)(MD / 1024)), dim3(256), 0, stream>>>(x, xb, (int)MD);
    dim3 tg(Dd / 64, Dd / 64, 4), bb(256);
    transpose_bf16<<<tg, bb, 0, stream>>>(Wq, Wk, Wv, Wo,
                                          Wqkvb, Wqkvb + WW, Wqkvb + 2 * WW, Wob);

    adj_to_bits<<<dim3(MTOT * 64 / 256), dim3(256), 0, stream>>>(adj, bitsbuf);

    // fused QKV projection: M=8192, N=1536, K=512
    gemm128<1, 16><<<dim3(MTOT / 128, 12, 1), bb, 0, stream>>>(
        xb, Wqkvb, bq, bk, bv, Qb, Kb, Vtb, nullptr, nullptr);

    attn_kernel<<<dim3(Bsz * Hh * (Nn / 64)), bb, 0, stream>>>(Qb, Kb, Vtb, bitsbuf, Ob);

    // O projection: M=8192, N=512, K=512, split-K x2 -> f32 partials hbuf/hbuf2
    gemm128<0, 8><<<dim3(MTOT / 128, 4, 2), bb, 0, stream>>>(
        Ob, Wob, bo, nullptr, nullptr, nullptr, nullptr, nullptr, hbuf, hbuf2);

    ln_kernel<<<dim3(MTOT), bb, 0, stream>>>(hbuf, hbuf2, x, gamma, beta, out);
}